// Round 3
// baseline (50.249 us; speedup 1.0000x reference)
//
#include <hip/hip_runtime.h>

// SparseCSREncoder roundtrip == elementwise threshold mask:
//   out[i] = (|x[i]| > 0.5f) ? x[i] : 0.0f
// Memory-bound streaming: 128 MiB in + 128 MiB out.
// Round 3: same as round 2 but use clang ext_vector_type(4) so the
// nontemporal builtins accept the pointer type.

#define THRESHOLD 0.5f

typedef float fx4 __attribute__((ext_vector_type(4)));

__device__ __forceinline__ fx4 mask4(fx4 v) {
    v.x = (fabsf(v.x) > THRESHOLD) ? v.x : 0.0f;
    v.y = (fabsf(v.y) > THRESHOLD) ? v.y : 0.0f;
    v.z = (fabsf(v.z) > THRESHOLD) ? v.z : 0.0f;
    v.w = (fabsf(v.w) > THRESHOLD) ? v.w : 0.0f;
    return v;
}

__global__ __launch_bounds__(256) void sparse_mask_kernel(
    const fx4* __restrict__ x, fx4* __restrict__ out, int n4) {
    int idx = blockIdx.x * blockDim.x + threadIdx.x;
    int stride = gridDim.x * blockDim.x;
    // unrolled-by-2 grid-stride: two independent float4 in flight per iter
    int i = idx;
    for (; i + stride < n4; i += 2 * stride) {
        fx4 a = __builtin_nontemporal_load(&x[i]);
        fx4 b = __builtin_nontemporal_load(&x[i + stride]);
        a = mask4(a);
        b = mask4(b);
        __builtin_nontemporal_store(a, &out[i]);
        __builtin_nontemporal_store(b, &out[i + stride]);
    }
    if (i < n4) {
        fx4 a = __builtin_nontemporal_load(&x[i]);
        __builtin_nontemporal_store(mask4(a), &out[i]);
    }
}

extern "C" void kernel_launch(void* const* d_in, const int* in_sizes, int n_in,
                              void* d_out, int out_size, void* d_ws, size_t ws_size,
                              hipStream_t stream) {
    const float* x = (const float*)d_in[0];
    float* out = (float*)d_out;
    int n = in_sizes[0];          // 33554432, divisible by 4
    int n4 = n / 4;

    const int block = 256;
    int grid = (n4 + block - 1) / block;
    if (grid > 4096) grid = 4096;

    sparse_mask_kernel<<<grid, block, 0, stream>>>(
        (const fx4*)x, (fx4*)out, n4);
}

// Round 4
// 41.988 us; speedup vs baseline: 1.1967x; 1.1967x over previous
//
#include <hip/hip_runtime.h>

// SparseCSREncoder roundtrip == elementwise threshold mask:
//   out[i] = (|x[i]| > 0.5f) ? x[i] : 0.0f
// Memory-bound streaming: 128 MiB in + 128 MiB out.
// Round 4: revert nontemporal (regressed 45.6->50.2). Exact-fit launch,
// one float4 per thread, no grid-stride loop.

#define THRESHOLD 0.5f

__global__ __launch_bounds__(256) void sparse_mask_kernel(
    const float4* __restrict__ x, float4* __restrict__ out) {
    int i = blockIdx.x * blockDim.x + threadIdx.x;
    float4 v = x[i];
    v.x = (fabsf(v.x) > THRESHOLD) ? v.x : 0.0f;
    v.y = (fabsf(v.y) > THRESHOLD) ? v.y : 0.0f;
    v.z = (fabsf(v.z) > THRESHOLD) ? v.z : 0.0f;
    v.w = (fabsf(v.w) > THRESHOLD) ? v.w : 0.0f;
    out[i] = v;
}

__global__ __launch_bounds__(256) void sparse_mask_tail(
    const float* __restrict__ x, float* __restrict__ out, int start, int n) {
    int i = start + blockIdx.x * blockDim.x + threadIdx.x;
    if (i < n) {
        float v = x[i];
        out[i] = (fabsf(v) > THRESHOLD) ? v : 0.0f;
    }
}

extern "C" void kernel_launch(void* const* d_in, const int* in_sizes, int n_in,
                              void* d_out, int out_size, void* d_ws, size_t ws_size,
                              hipStream_t stream) {
    const float* x = (const float*)d_in[0];
    float* out = (float*)d_out;
    int n = in_sizes[0];          // 33554432
    int n4 = n / 4;               // 8388608 = 32768 * 256
    const int block = 256;
    int grid = n4 / block;        // exact for this size

    sparse_mask_kernel<<<grid, block, 0, stream>>>(
        (const float4*)x, (float4*)out);

    // tail (not hit for 32M, but keep deterministic correctness for any n)
    int done = grid * block * 4;
    if (done < n) {
        int rem = n - done;
        sparse_mask_tail<<<(rem + block - 1) / block, block, 0, stream>>>(
            x, out, done, n);
    }
}